// Round 6
// baseline (848.626 us; speedup 1.0000x reference)
//
#include <hip/hip_runtime.h>

#define NNODES 100000
#define F 256
#define SCB 1024                          // nodes per scan block
#define NSCB ((NNODES + SCB - 1) / SCB)   // 98 scan blocks

typedef unsigned short u16;
typedef unsigned int   u32;
typedef __attribute__((ext_vector_type(8))) short short8v;          // 8 bf16
typedef __attribute__((ext_vector_type(8))) unsigned short ushort8; // 8 bf16 bits
typedef __attribute__((ext_vector_type(4))) float f32x4;
typedef __attribute__((ext_vector_type(2))) float f32x2;

__device__ __forceinline__ u16 f2bf(float f) {
    u32 u = __float_as_uint(f);
    u32 r = u + 0x7FFFu + ((u >> 16) & 1u);   // round-to-nearest-even
    return (u16)(r >> 16);
}

// ---------------- cast W -> bf16 + zero deg (fused) ----------------
__global__ __launch_bounds__(256) void cast_w_zero(const float* __restrict__ W,
                                                   u16* __restrict__ Wb,
                                                   int* __restrict__ deg) {
    int i = blockIdx.x * 256 + threadIdx.x;
    if (i < F * F / 4) {
        float4 w = ((const float4*)W)[i];
        ushort4 o;
        o.x = f2bf(w.x); o.y = f2bf(w.y); o.z = f2bf(w.z); o.w = f2bf(w.w);
        ((ushort4*)Wb)[i] = o;
    }
    if (i < NNODES) deg[i] = 0;
}

// ---------------- GEMM: Yb = bf16( X @ Wb^T ), X cast to bf16 in-register ----
__global__ __launch_bounds__(256) void gemm_mfma(const float* __restrict__ X,
                                                 const u16* __restrict__ Wb,
                                                 u16* __restrict__ Yb) {
    const int wave = threadIdx.x >> 6;
    const int lane = threadIdx.x & 63;
    const int lm   = lane & 15;
    const int kg   = lane >> 4;
    const int m0   = blockIdx.x * 128 + wave * 32;
    const int n0   = blockIdx.y * 128;

    f32x4 acc[2][8];
#pragma unroll
    for (int t = 0; t < 2; ++t)
#pragma unroll
        for (int u = 0; u < 8; ++u) acc[t][u] = (f32x4){0.f, 0.f, 0.f, 0.f};

    int rowA[2];
#pragma unroll
    for (int t = 0; t < 2; ++t) {
        int row = m0 + t * 16 + lm;
        rowA[t] = (row < NNODES) ? row : NNODES - 1;
    }

    for (int k0 = 0; k0 < F; k0 += 32) {
        const int kb = k0 + kg * 8;
        short8v aF[2];
#pragma unroll
        for (int t = 0; t < 2; ++t) {
            const float* xr = X + (size_t)rowA[t] * F + kb;
            float4 x0 = *(const float4*)xr;
            float4 x1 = *(const float4*)(xr + 4);
            short8v a;
            a[0] = (short)f2bf(x0.x); a[1] = (short)f2bf(x0.y);
            a[2] = (short)f2bf(x0.z); a[3] = (short)f2bf(x0.w);
            a[4] = (short)f2bf(x1.x); a[5] = (short)f2bf(x1.y);
            a[6] = (short)f2bf(x1.z); a[7] = (short)f2bf(x1.w);
            aF[t] = a;
        }
        short8v bF[8];
#pragma unroll
        for (int u = 0; u < 8; ++u)
            bF[u] = *(const short8v*)(Wb + (size_t)(n0 + u * 16 + lm) * F + kb);
#pragma unroll
        for (int t = 0; t < 2; ++t)
#pragma unroll
            for (int u = 0; u < 8; ++u)
                acc[t][u] = __builtin_amdgcn_mfma_f32_16x16x32_bf16(aF[t], bF[u], acc[t][u], 0, 0, 0);
    }

    // D layout (16x16x32): col = lane&15, row = (lane>>4)*4 + i
#pragma unroll
    for (int t = 0; t < 2; ++t) {
        int rbase = m0 + t * 16 + kg * 4;
#pragma unroll
        for (int i = 0; i < 4; ++i) {
            int row = rbase + i;
            if (row < NNODES) {
#pragma unroll
                for (int u = 0; u < 8; ++u)
                    Yb[(size_t)row * F + n0 + u * 16 + lm] = f2bf(acc[t][u][i]);
            }
        }
    }
}

// ---------------- CSR build step 1: per-node degree ----------------
__global__ __launch_bounds__(256) void count_deg(const int* __restrict__ src,
                                                 int* __restrict__ deg, int n_edges) {
    int stride = gridDim.x * 256;
    for (int e = blockIdx.x * 256 + threadIdx.x; e < n_edges; e += stride)
        atomicAdd(&deg[src[e]], 1);
}

// ---------------- CSR step 2a: per-1024-node partial scan ----------------
// nodeseg[n] = (local exclusive prefix, deg) ; bsum[b] = block total
__global__ __launch_bounds__(256) void scan_part(const int* __restrict__ deg,
                                                 int2* __restrict__ nodeseg,
                                                 int* __restrict__ bsum) {
    __shared__ int ts[256];
    const int t = threadIdx.x;
    const int n0 = blockIdx.x * SCB + t * 4;
    int d0 = 0, d1 = 0, d2 = 0, d3 = 0;
    if (n0 + 0 < NNODES) d0 = deg[n0 + 0];
    if (n0 + 1 < NNODES) d1 = deg[n0 + 1];
    if (n0 + 2 < NNODES) d2 = deg[n0 + 2];
    if (n0 + 3 < NNODES) d3 = deg[n0 + 3];
    int sum = d0 + d1 + d2 + d3;
    ts[t] = sum;
    __syncthreads();
    for (int off = 1; off < 256; off <<= 1) {
        int x = (t >= off) ? ts[t - off] : 0;
        __syncthreads();
        ts[t] += x;
        __syncthreads();
    }
    int p = ts[t] - sum;                 // exclusive offset within block
    if (t == 255) bsum[blockIdx.x] = ts[255];
    if (n0 + 0 < NNODES) nodeseg[n0 + 0] = make_int2(p, d0);
    p += d0;
    if (n0 + 1 < NNODES) nodeseg[n0 + 1] = make_int2(p, d1);
    p += d1;
    if (n0 + 2 < NNODES) nodeseg[n0 + 2] = make_int2(p, d2);
    p += d2;
    if (n0 + 3 < NNODES) nodeseg[n0 + 3] = make_int2(p, d3);
}

// ---------------- CSR step 2b: scan the 98 block sums (1 block) ----------------
__global__ __launch_bounds__(256) void scan_top(int* __restrict__ bsum) {
    __shared__ int s[256];
    const int t = threadIdx.x;
    int v = (t < NSCB) ? bsum[t] : 0;
    s[t] = v;
    __syncthreads();
    for (int off = 1; off < 256; off <<= 1) {
        int x = (t >= off) ? s[t - off] : 0;
        __syncthreads();
        s[t] += x;
        __syncthreads();
    }
    if (t < NSCB) bsum[t] = s[t] - v;    // exclusive
}

// ---------------- CSR step 2c: add block offsets, emit nodeseg + cursor ------
__global__ __launch_bounds__(256) void scan_add(int2* __restrict__ nodeseg,
                                                const int* __restrict__ bsum,
                                                int* __restrict__ cursor) {
    const int boff = bsum[blockIdx.x];
    const int n0 = blockIdx.x * SCB + threadIdx.x * 4;
#pragma unroll
    for (int i = 0; i < 4; ++i) {
        int n = n0 + i;
        if (n < NNODES) {
            int2 pd = nodeseg[n];
            int start = pd.x + boff;
            nodeseg[n] = make_int2(start, start + pd.y);
            cursor[n] = start;
        }
    }
}

// ---------------- CSR step 3: scatter edges directly into pack ----------------
// pack.x = dst*512 (pre-scaled byte offset into Yb), pack.y = val bits.
__global__ __launch_bounds__(256) void fill_pack(const int* __restrict__ src,
                                                 const int* __restrict__ dst,
                                                 const float* __restrict__ val,
                                                 int* __restrict__ cursor,
                                                 int2* __restrict__ pack, int n_edges) {
    int stride = gridDim.x * 256;
    for (int e = blockIdx.x * 256 + threadIdx.x; e < n_edges; e += stride) {
        int s = src[e];
        int pos = atomicAdd(&cursor[s], 1);
        pack[pos] = make_int2(dst[e] << 9, __float_as_int(val[e]));
    }
}

// ---------------- Gather: out[node] = b + sum val * Y[dst]  (bf16 Y) --------
// One wave per node; halves handle even/odd edges; lane owns 8 feats (16 B).
// Measured floor ~224 us across 3 schedule variants (memory-system-bound).
__global__ __launch_bounds__(256) void gather_nodes(const int2* __restrict__ nodeseg,
                                                    const int2* __restrict__ pack,
                                                    const u16* __restrict__ Yb,
                                                    const float* __restrict__ bias,
                                                    float* __restrict__ out) {
    int node = blockIdx.x * 4 + (threadIdx.x >> 6);
    if (node >= NNODES) return;
    const int lane = threadIdx.x & 63;
    const int half = lane >> 5;
    const int l5   = lane & 31;
    const u32 loff = (u32)l5 * 16u;          // lane's byte offset within a row
    const char* Ybc = (const char*)Yb;

    int2 seg = nodeseg[node];
    const int beg = seg.x, end = seg.y;

    f32x2 acc2[4];
#pragma unroll
    for (int i = 0; i < 4; ++i) acc2[i] = (f32x2){0.f, 0.f};

    for (int j = beg; j < end; j += 16) {     // 8 pairs = 16 edges per iter
        u32 off[8];
        float v[8];
        ushort8 y[8];
#pragma unroll
        for (int q = 0; q < 8; ++q) {
            int idx = j + 2 * q + half;
            int safe = idx < end ? idx : end - 1;
            long long raw = __builtin_nontemporal_load((const long long*)&pack[safe]);
            off[q] = (u32)((unsigned long long)raw & 0xFFFFFFFFull);
            v[q] = (idx < end) ? __int_as_float((int)(raw >> 32)) : 0.f;
        }
#pragma unroll
        for (int q = 0; q < 8; ++q)
            y[q] = *(const ushort8*)(Ybc + (off[q] + loff));
#pragma unroll
        for (int q = 0; q < 8; ++q) {
            f32x2 vv; vv[0] = v[q]; vv[1] = v[q];
            const u32* yp = (const u32*)&y[q];
#pragma unroll
            for (int i = 0; i < 4; ++i) {
                u32 pb = yp[i];
                f32x2 yy;
                yy[0] = __uint_as_float(pb << 16);
                yy[1] = __uint_as_float(pb & 0xFFFF0000u);
                acc2[i] = __builtin_elementwise_fma(yy, vv, acc2[i]);
            }
        }
    }

    float acc[8];
#pragma unroll
    for (int i = 0; i < 4; ++i) { acc[2 * i] = acc2[i][0]; acc[2 * i + 1] = acc2[i][1]; }
    // combine halves
#pragma unroll
    for (int i = 0; i < 8; ++i) acc[i] += __shfl_xor(acc[i], 32);

    // bias + store: lane writes feats [l5*8 + half*4 .. +3]
    const int col = l5 * 8 + half * 4;
    float4 bv = *(const float4*)&bias[col];
    f32x4 o;
    o[0] = acc[half * 4 + 0] + bv.x;
    o[1] = acc[half * 4 + 1] + bv.y;
    o[2] = acc[half * 4 + 2] + bv.z;
    o[3] = acc[half * 4 + 3] + bv.w;
    __builtin_nontemporal_store(o, (f32x4*)&out[(size_t)node * F + col]);
}

extern "C" void kernel_launch(void* const* d_in, const int* in_sizes, int n_in,
                              void* d_out, int out_size, void* d_ws, size_t ws_size,
                              hipStream_t stream) {
    const float* X        = (const float*)d_in[0];
    const int*   edge_src = (const int*)d_in[1];
    const int*   edge_dst = (const int*)d_in[2];
    const float* edge_val = (const float*)d_in[3];
    const float* W        = (const float*)d_in[4];
    const float* b        = (const float*)d_in[5];
    float*       out      = (float*)d_out;
    const int n_edges     = in_sizes[1];

    // Workspace (~79 MB): Yb | pack | Wb | nodeseg | deg | cursor | bsum
    char* base = (char*)d_ws;
    const size_t ybBytes   = (size_t)NNODES * F * sizeof(u16);     // 51.2 MB
    const size_t packBytes = (size_t)n_edges * sizeof(int2);       // 25.6 MB (tight)
    u16*  Yb      = (u16*)base;
    int2* pack    = (int2*)(base + ybBytes);
    u16*  Wb      = (u16*)(base + ybBytes + packBytes);
    int2* nodeseg = (int2*)((char*)Wb + (size_t)F * F * sizeof(u16));
    int*  deg     = (int*)(nodeseg + NNODES);
    int*  cursor  = deg + NNODES;
    int*  bsum    = cursor + NNODES;

    // 1) W cast + deg zero (fused)
    cast_w_zero<<<(NNODES + 255) / 256, 256, 0, stream>>>(W, Wb, deg);

    // 2) Yb = bf16(X @ Wb^T) via MFMA (X cast in-register)
    dim3 ggrid((NNODES + 127) / 128, F / 128);
    gemm_mfma<<<ggrid, 256, 0, stream>>>(X, Wb, Yb);

    // 3) CSR build: degree count -> 3-step scan -> direct scatter into pack
    count_deg<<<1024, 256, 0, stream>>>(edge_src, deg, n_edges);
    scan_part<<<NSCB, 256, 0, stream>>>(deg, nodeseg, bsum);
    scan_top<<<1, 256, 0, stream>>>(bsum);
    scan_add<<<NSCB, 256, 0, stream>>>(nodeseg, bsum, cursor);
    fill_pack<<<1024, 256, 0, stream>>>(edge_src, edge_dst, edge_val, cursor, pack, n_edges);

    // 4) Gather + bias
    gather_nodes<<<(NNODES + 3) / 4, 256, 0, stream>>>(nodeseg, pack, Yb, b, out);
}

// Round 7
// 552.601 us; speedup vs baseline: 1.5357x; 1.5357x over previous
//
#include <hip/hip_runtime.h>

#define NNODES 100000
#define F 256
#define NBKT ((NNODES + 127) / 128)    // 782 buckets of 128 src nodes
#define BKT_CAP 5120                   // mean 4092, +16 sigma; P(overflow) ~ 1e-13
#define CHUNK_A 8192                   // edges per bin_edges block

typedef unsigned short u16;
typedef unsigned int   u32;
typedef __attribute__((ext_vector_type(8))) short short8v;          // 8 bf16
typedef __attribute__((ext_vector_type(8))) unsigned short ushort8; // 8 bf16 bits
typedef __attribute__((ext_vector_type(4))) float f32x4;
typedef __attribute__((ext_vector_type(2))) float f32x2;

__device__ __forceinline__ u16 f2bf(float f) {
    u32 u = __float_as_uint(f);
    u32 r = u + 0x7FFFu + ((u >> 16) & 1u);   // round-to-nearest-even
    return (u16)(r >> 16);
}

// ---------------- cast W -> bf16 + init bucket cursors (fused) ----------------
__global__ __launch_bounds__(256) void cast_w_init(const float* __restrict__ W,
                                                   u16* __restrict__ Wb,
                                                   int* __restrict__ cur) {
    int i = blockIdx.x * 256 + threadIdx.x;
    if (i < F * F / 4) {
        float4 w = ((const float4*)W)[i];
        ushort4 o;
        o.x = f2bf(w.x); o.y = f2bf(w.y); o.z = f2bf(w.z); o.w = f2bf(w.w);
        ((ushort4*)Wb)[i] = o;
    }
    if (i < NBKT) cur[i] = i * BKT_CAP;
}

// ---------------- cast X -> bf16 (streaming) ----------------
__global__ __launch_bounds__(256) void cast_x(const float* __restrict__ X,
                                              u16* __restrict__ Xb, int total4) {
    int i = blockIdx.x * 256 + threadIdx.x;
    if (i >= total4) return;
    float4 x = ((const float4*)X)[i];
    ushort4 o;
    o.x = f2bf(x.x); o.y = f2bf(x.y); o.z = f2bf(x.z); o.w = f2bf(x.w);
    ((ushort4*)Xb)[i] = o;
}

// ---------------- GEMM: Yb = bf16( Xb @ Wb^T ) via MFMA, LDS-staged ----------
// 128x128 tile, K staged in two 128-wide K-tiles. A+B = 64 KB LDS -> 2 blk/CU.
// 16B-chunk XOR swizzle (chunk ^= row&7) keeps ds_read_b128 <=2-way (free).
// Fragment->lane mapping identical to the verified global-read kernel.
__global__ __launch_bounds__(256) void gemm_mfma(const u16* __restrict__ Xb,
                                                 const u16* __restrict__ Wb,
                                                 u16* __restrict__ Yb) {
    __shared__ u16 As[128 * 128];   // 32 KB
    __shared__ u16 Bs[128 * 128];   // 32 KB
    const int wv   = threadIdx.x >> 6;
    const int lane = threadIdx.x & 63;
    const int lm   = lane & 15;
    const int kg   = lane >> 4;
    const int m0   = blockIdx.x * 128;
    const int n0   = blockIdx.y * 128;

    f32x4 acc[2][8];
#pragma unroll
    for (int t = 0; t < 2; ++t)
#pragma unroll
        for (int u = 0; u < 8; ++u) acc[t][u] = (f32x4){0.f, 0.f, 0.f, 0.f};

#pragma unroll
    for (int kt = 0; kt < 2; ++kt) {
        if (kt) __syncthreads();          // protect LDS before overwrite
        // stage A,B: 2048 16B-chunks each; thread copies 8 chunks per tile.
        // chunk q -> row = q/16, local chunk cl = q%16, source chunk cs = cl^(row&7)
#pragma unroll
        for (int i = 0; i < 8; ++i) {
            int q   = i * 256 + threadIdx.x;
            int row = q >> 4;
            int cs  = (q & 15) ^ (row & 7);
            size_t goff = (size_t)row * 512 + kt * 256 + cs * 16;   // bytes
            *(ushort8*)&As[q * 8] = *(const ushort8*)((const char*)Xb + (size_t)m0 * 512 + goff);
            *(ushort8*)&Bs[q * 8] = *(const ushort8*)((const char*)Wb + (size_t)n0 * 512 + goff);
        }
        __syncthreads();
#pragma unroll
        for (int s = 0; s < 4; ++s) {     // 4 k-steps of 32 per K-tile
            short8v aF[2];
#pragma unroll
            for (int t = 0; t < 2; ++t) {
                int r = wv * 32 + t * 16 + lm;
                int c = (s * 4 + kg) ^ (r & 7);
                aF[t] = *(const short8v*)&As[r * 128 + c * 8];
            }
            short8v bF[8];
#pragma unroll
            for (int u = 0; u < 8; ++u) {
                int r = u * 16 + lm;
                int c = (s * 4 + kg) ^ (r & 7);
                bF[u] = *(const short8v*)&Bs[r * 128 + c * 8];
            }
#pragma unroll
            for (int t = 0; t < 2; ++t)
#pragma unroll
                for (int u = 0; u < 8; ++u)
                    acc[t][u] = __builtin_amdgcn_mfma_f32_16x16x32_bf16(aF[t], bF[u], acc[t][u], 0, 0, 0);
        }
    }

    // D layout (16x16x32): col = lane&15, row = (lane>>4)*4 + i
#pragma unroll
    for (int t = 0; t < 2; ++t) {
        int rbase = m0 + wv * 32 + t * 16 + kg * 4;
#pragma unroll
        for (int i = 0; i < 4; ++i) {
            int row = rbase + i;
            if (row < NNODES) {
#pragma unroll
                for (int u = 0; u < 8; ++u)
                    Yb[(size_t)row * F + n0 + u * 16 + lm] = f2bf(acc[t][u][i]);
            }
        }
    }
}

// ---------------- Phase A: bin edges into 128-node buckets ----------------
// temp[pos] = ( (src&127)<<20 | dst , val_bits ), bucket-strided regions.
// src read once: (l:13 | (src&127):7 | bkt:10) packed in registers.
__global__ __launch_bounds__(256) void bin_edges(const int* __restrict__ src,
                                                 const int* __restrict__ dst,
                                                 const float* __restrict__ val,
                                                 int* __restrict__ cur,
                                                 int2* __restrict__ temp,
                                                 int n_edges) {
    __shared__ int hist[NBKT];
    __shared__ int bas[NBKT];
    const int e0 = blockIdx.x * CHUNK_A;
    for (int i = threadIdx.x; i < NBKT; i += 256) hist[i] = 0;
    __syncthreads();

    u32 lpk[32];
#pragma unroll
    for (int k = 0; k < 32; ++k) {
        int e = e0 + k * 256 + threadIdx.x;
        if (e < n_edges) {
            int s = src[e];
            int bkt = s >> 7;
            int l = atomicAdd(&hist[bkt], 1);          // < 8192, fits 13 bits
            lpk[k] = (u32)l | ((u32)(s & 127) << 13) | ((u32)bkt << 20);
        }
    }
    __syncthreads();
    for (int i = threadIdx.x; i < NBKT; i += 256) {
        int c = hist[i];
        bas[i] = c ? atomicAdd(&cur[i], c) : 0;
    }
    __syncthreads();
#pragma unroll
    for (int k = 0; k < 32; ++k) {
        int e = e0 + k * 256 + threadIdx.x;
        if (e < n_edges) {
            u32 p   = lpk[k];
            int bkt = (int)(p >> 20);
            int pos = bas[bkt] + (int)(p & 0x1FFFu);
            int sl  = (int)((p >> 13) & 127u);
            temp[pos] = make_int2((sl << 20) | dst[e], __float_as_int(val[e]));
        }
    }
}

// ---------------- Phase B: per-bucket node sort + nodeseg emit ----------------
// Bucket staged in LDS (one global read instead of two); pack.x holds the
// PRE-SCALED byte offset dst*512 so gather needs no 64-bit address math.
__global__ __launch_bounds__(256) void sort_bucket(const int* __restrict__ cur,
                                                   const int2* __restrict__ temp,
                                                   int2* __restrict__ pack,
                                                   int2* __restrict__ nodeseg) {
    __shared__ int2 tl[BKT_CAP];     // 40 KB
    __shared__ int h[128];
    __shared__ int curl[128];
    const int b = blockIdx.x;
    const int base = b * BKT_CAP;
    int cnt = cur[b] - base;
    if (cnt > BKT_CAP) cnt = BKT_CAP;   // overflow guard (P ~ 1e-13)
    const int tid = threadIdx.x;

    if (tid < 128) h[tid] = 0;
    __syncthreads();
    for (int j = tid; j < cnt; j += 256) {     // stage + histogram in one pass
        int2 t = temp[base + j];
        tl[j] = t;
        atomicAdd(&h[t.x >> 20], 1);
    }
    __syncthreads();
    // inclusive scan over 128 entries
    for (int off = 1; off < 128; off <<= 1) {
        int x = 0;
        if (tid < 128 && tid >= off) x = h[tid - off];
        __syncthreads();
        if (tid < 128) h[tid] += x;
        __syncthreads();
    }
    if (tid < 128) {
        int incl = h[tid];
        int prev = tid ? h[tid - 1] : 0;
        curl[tid] = base + prev;
        int node = b * 128 + tid;
        if (node < NNODES) nodeseg[node] = make_int2(base + prev, base + incl);
    }
    __syncthreads();
    for (int j = tid; j < cnt; j += 256) {
        int2 p = tl[j];
        int loc = p.x >> 20;
        int pos = atomicAdd(&curl[loc], 1);
        pack[pos] = make_int2((p.x & 0xFFFFF) << 9, p.y);   // dst*512 byte offset
    }
}

// ---------------- Gather: out[node] = b + sum val * Y[dst]  (bf16 Y) --------
// One wave per node; halves handle even/odd edges; lane owns 8 feats (16 B).
// Measured floor ~224 us across 3 schedule variants (memory-system-bound).
__global__ __launch_bounds__(256) void gather_nodes(const int2* __restrict__ nodeseg,
                                                    const int2* __restrict__ pack,
                                                    const u16* __restrict__ Yb,
                                                    const float* __restrict__ bias,
                                                    float* __restrict__ out) {
    int node = blockIdx.x * 4 + (threadIdx.x >> 6);
    if (node >= NNODES) return;
    const int lane = threadIdx.x & 63;
    const int half = lane >> 5;
    const int l5   = lane & 31;
    const u32 loff = (u32)l5 * 16u;          // lane's byte offset within a row
    const char* Ybc = (const char*)Yb;

    int2 seg = nodeseg[node];
    const int beg = seg.x, end = seg.y;

    f32x2 acc2[4];
#pragma unroll
    for (int i = 0; i < 4; ++i) acc2[i] = (f32x2){0.f, 0.f};

    for (int j = beg; j < end; j += 16) {     // 8 pairs = 16 edges per iter
        u32 off[8];
        float v[8];
        ushort8 y[8];
#pragma unroll
        for (int q = 0; q < 8; ++q) {
            int idx = j + 2 * q + half;
            int safe = idx < end ? idx : end - 1;
            long long raw = __builtin_nontemporal_load((const long long*)&pack[safe]);
            off[q] = (u32)((unsigned long long)raw & 0xFFFFFFFFull);
            v[q] = (idx < end) ? __int_as_float((int)(raw >> 32)) : 0.f;
        }
#pragma unroll
        for (int q = 0; q < 8; ++q)
            y[q] = *(const ushort8*)(Ybc + (off[q] + loff));
#pragma unroll
        for (int q = 0; q < 8; ++q) {
            f32x2 vv; vv[0] = v[q]; vv[1] = v[q];
            const u32* yp = (const u32*)&y[q];
#pragma unroll
            for (int i = 0; i < 4; ++i) {
                u32 pb = yp[i];
                f32x2 yy;
                yy[0] = __uint_as_float(pb << 16);
                yy[1] = __uint_as_float(pb & 0xFFFF0000u);
                acc2[i] = __builtin_elementwise_fma(yy, vv, acc2[i]);
            }
        }
    }

    float acc[8];
#pragma unroll
    for (int i = 0; i < 4; ++i) { acc[2 * i] = acc2[i][0]; acc[2 * i + 1] = acc2[i][1]; }
    // combine halves
#pragma unroll
    for (int i = 0; i < 8; ++i) acc[i] += __shfl_xor(acc[i], 32);

    // bias + store: lane writes feats [l5*8 + half*4 .. +3]
    const int col = l5 * 8 + half * 4;
    float4 bv = *(const float4*)&bias[col];
    f32x4 o;
    o[0] = acc[half * 4 + 0] + bv.x;
    o[1] = acc[half * 4 + 1] + bv.y;
    o[2] = acc[half * 4 + 2] + bv.z;
    o[3] = acc[half * 4 + 3] + bv.w;
    __builtin_nontemporal_store(o, (f32x4*)&out[(size_t)node * F + col]);
}

extern "C" void kernel_launch(void* const* d_in, const int* in_sizes, int n_in,
                              void* d_out, int out_size, void* d_ws, size_t ws_size,
                              hipStream_t stream) {
    const float* X        = (const float*)d_in[0];
    const int*   edge_src = (const int*)d_in[1];
    const int*   edge_dst = (const int*)d_in[2];
    const float* edge_val = (const float*)d_in[3];
    const float* W        = (const float*)d_in[4];
    const float* b        = (const float*)d_in[5];
    float*       out      = (float*)d_out;
    const int n_edges     = in_sizes[1];

    // Workspace (~116.2 MB). Xb (51.25 MB incl. 128-row OOB pad for the edge
    // tile) overlays pack+temp (64.1 MB): Xb is dead after gemm; temp/pack are
    // written only after gemm.
    char* base = (char*)d_ws;
    const size_t ybBytes   = (size_t)NNODES * F * sizeof(u16);        // 51.2 MB
    const size_t packBytes = (size_t)NBKT * BKT_CAP * sizeof(int2);   // 32.03 MB
    u16*  Yb      = (u16*)base;
    int2* pack    = (int2*)(base + ybBytes);
    int2* temp    = (int2*)(base + ybBytes + packBytes);
    u16*  Xb      = (u16*)pack;                                       // overlay
    u16*  Wb      = (u16*)(base + ybBytes + 2 * packBytes);
    int2* nodeseg = (int2*)((char*)Wb + (size_t)F * F * sizeof(u16));
    int*  cur     = (int*)(nodeseg + NNODES);

    // 1) W cast + cursor init (fused); X cast
    cast_w_init<<<(F * F / 4 + 255) / 256, 256, 0, stream>>>(W, Wb, cur);
    int xt4 = NNODES * F / 4;
    cast_x<<<(xt4 + 255) / 256, 256, 0, stream>>>(X, Xb, xt4);

    // 2) Yb = bf16(Xb @ Wb^T) via LDS-staged MFMA
    dim3 ggrid((NNODES + 127) / 128, F / 128);
    gemm_mfma<<<ggrid, 256, 0, stream>>>(Xb, Wb, Yb);

    // 3) two-phase binned counting sort (no global scan)
    bin_edges<<<(n_edges + CHUNK_A - 1) / CHUNK_A, 256, 0, stream>>>(edge_src, edge_dst, edge_val,
                                                                     cur, temp, n_edges);
    sort_bucket<<<NBKT, 256, 0, stream>>>(cur, temp, pack, nodeseg);

    // 4) Gather + bias
    gather_nodes<<<(NNODES + 3) / 4, 256, 0, stream>>>(nodeseg, pack, Yb, b, out);
}